// Round 1
// baseline (4240.792 us; speedup 1.0000x reference)
//
#include <hip/hip_runtime.h>

// RallyNet: latent-SDE. T=100 steps, B=4096, D=32, L=32, C=64, H=128.
// Parallel over batch only; two persistent kernels loop over time.
// f16 weights+activations in LDS, v_dot2_f32_f16 MACs, f32 accumulation.
// ctx[t,b,:] (f16) is staged INSIDE d_out, aliased byte-for-byte with
// xs_hat[t,b,:] (f32): kernel2 reads ctx[t] before overwriting with xs_hat[t].

#define TT 100
#define BB 4096
#define DD 32
#define LL 32
#define CC 64
#define HH 128

typedef _Float16 h1;
typedef _Float16 h2 __attribute__((ext_vector_type(2)));

__device__ __forceinline__ float fdot2(h2 a, h2 b, float c) {
#if __has_builtin(__builtin_amdgcn_fdot2)
  return __builtin_amdgcn_fdot2(a, b, c, false);
#else
  return c + (float)a[0] * (float)b[0] + (float)a[1] * (float)b[1];
#endif
}

__device__ __forceinline__ float sigm(float x) {
  return 1.0f / (1.0f + __expf(-x));
}
__device__ __forceinline__ float tanh_(float x) {
  float xc = fminf(fmaxf(x, -15.0f), 15.0f);
  float e = __expf(2.0f * xc);
  return (e - 1.0f) / (e + 1.0f);
}
__device__ __forceinline__ float splus(float x) {
  float t = __logf(1.0f + __expf(fminf(x, 15.0f)));
  return x > 15.0f ? x : t;
}

// ---------------- Kernel 1: GRU encoder + Linear(ctx) ----------------
// 256 blocks x 512 threads; block owns 16 batch rows for all 100 steps.
// thread (r = tid&15, c = tid>>4): row r, hidden-unit group {c+32i}.
__global__ __launch_bounds__(512, 2) void k_gru(
    const float* __restrict__ xs, const float* __restrict__ Wih,
    const float* __restrict__ Whh, const float* __restrict__ bih,
    const float* __restrict__ bhh, const float* __restrict__ encW,
    const float* __restrict__ encb, h1* __restrict__ ctx16) {
  __shared__ h1 sWhh[384][136];   // pad 128->136: rows 272B (16B aligned, banks spread)
  __shared__ h1 sWih[384][32];
  __shared__ h1 sEnc[64][136];
  __shared__ float sBih[384], sBhh[384], sEncB[64];
  __shared__ h1 sH[16][136];
  __shared__ h1 sX[16][40];

  const int tid = threadIdx.x;
  const int r = tid & 15, c = tid >> 4;  // c in 0..31
  const int b0 = blockIdx.x * 16;

  for (int i = tid; i < 384 * 128; i += 512) sWhh[i >> 7][i & 127] = (h1)Whh[i];
  for (int i = tid; i < 384 * 32; i += 512) sWih[i >> 5][i & 31] = (h1)Wih[i];
  for (int i = tid; i < 64 * 128; i += 512) sEnc[i >> 7][i & 127] = (h1)encW[i];
  for (int i = tid; i < 384; i += 512) { sBih[i] = bih[i]; sBhh[i] = bhh[i]; }
  if (tid < 64) sEncB[tid] = encb[tid];
  for (int i = tid; i < 16 * 136; i += 512) ((h1*)sH)[i] = (h1)0.0f;
  __syncthreads();

  for (int t = 0; t < TT; ++t) {
    // stage x[t] for our 16 rows (512 contiguous floats, 1 per thread)
    sX[tid >> 5][tid & 31] = (h1)xs[(size_t)t * BB * DD + (size_t)b0 * DD + tid];
    __syncthreads();

    h2 hreg[64];
    const h2* hrow = (const h2*)sH[r];
#pragma unroll
    for (int k = 0; k < 64; ++k) hreg[k] = hrow[k];
    h2 xreg[16];
    const h2* xrow = (const h2*)sX[r];
#pragma unroll
    for (int k = 0; k < 16; ++k) xreg[k] = xrow[k];

    float hnew[4];
#pragma unroll
    for (int i = 0; i < 4; ++i) {
      const int m = c + 32 * i;
      float ai[3], ah[3];
#pragma unroll
      for (int g = 0; g < 3; ++g) {
        const int j = g * 128 + m;
        const h2* wi = (const h2*)sWih[j];
        const h2* wh = (const h2*)sWhh[j];
        float a0 = 0.f, a1 = 0.f;
#pragma unroll
        for (int k = 0; k < 16; k += 2) {
          a0 = fdot2(wi[k], xreg[k], a0);
          a1 = fdot2(wi[k + 1], xreg[k + 1], a1);
        }
        float b0a = 0.f, b1a = 0.f;
#pragma unroll
        for (int k = 0; k < 64; k += 2) {
          b0a = fdot2(wh[k], hreg[k], b0a);
          b1a = fdot2(wh[k + 1], hreg[k + 1], b1a);
        }
        ai[g] = a0 + a1 + sBih[j];
        ah[g] = b0a + b1a + sBhh[j];
      }
      float rg = sigm(ai[0] + ah[0]);
      float zg = sigm(ai[1] + ah[1]);
      float ng = tanh_(ai[2] + rg * ah[2]);
      float hold = (float)sH[r][m];          // pre-update h (no writes until barrier)
      hnew[i] = (1.0f - zg) * ng + zg * hold;
    }
    __syncthreads();  // all gh dot-reads of sH complete
#pragma unroll
    for (int i = 0; i < 4; ++i) sH[r][c + 32 * i] = (h1)hnew[i];
    __syncthreads();  // h fully updated

    // encoder: ctx cols {2c, 2c+1}; reload updated h row
#pragma unroll
    for (int k = 0; k < 64; ++k) hreg[k] = hrow[k];
    {
      const int c0 = 2 * c, c1 = 2 * c + 1;
      float e0 = sEncB[c0], e1 = sEncB[c1];
      const h2* w0 = (const h2*)sEnc[c0];
      const h2* w1 = (const h2*)sEnc[c1];
#pragma unroll
      for (int k = 0; k < 64; ++k) {
        e0 = fdot2(w0[k], hreg[k], e0);
        e1 = fdot2(w1[k], hreg[k], e1);
      }
      h2 o;
      o[0] = (h1)e0;
      o[1] = (h1)e1;
      *(h2*)(ctx16 + ((size_t)t * BB + b0 + r) * CC + c0) = o;
    }
  }
}

// ---------------- Kernel 2: posterior z0 + SDE scan + projection ----------------
// 256 blocks x 512 threads; thread (r = tid&15, c = tid>>4): row r, latent/col group.
__global__ __launch_bounds__(512, 2) void k_sde(
    const float* __restrict__ ts, const float* __restrict__ eps0,
    const float* __restrict__ noise, const float* __restrict__ qz0W,
    const float* __restrict__ qz0b, const float* __restrict__ fW1,
    const float* __restrict__ fb1, const float* __restrict__ fW2,
    const float* __restrict__ fb2, const float* __restrict__ fW3,
    const float* __restrict__ fb3, const float* __restrict__ hW1,
    const float* __restrict__ hb1, const float* __restrict__ hW2,
    const float* __restrict__ hb2, const float* __restrict__ hW3,
    const float* __restrict__ hb3, const float* __restrict__ gW1,
    const float* __restrict__ gb1, const float* __restrict__ gW2,
    const float* __restrict__ gb2, const float* __restrict__ projW,
    const float* __restrict__ projb, const h1* __restrict__ ctx16,
    float* __restrict__ out) {
  __shared__ h1 sFW1[128][104];  // 96 -> 104 pad
  __shared__ h1 sFW2[128][136];
  __shared__ h1 sHW1[128][40];
  __shared__ h1 sHW2[128][136];
  __shared__ h1 sFW3[32][136];
  __shared__ h1 sHW3[32][136];
  __shared__ float sFB1[128], sFB2[128], sFB3[32];
  __shared__ float sHB1[128], sHB2[128], sHB3[32];
  __shared__ h1 sYC[16][104];    // [y(32) ; ctx(64)] per row, f16
  __shared__ float sY32[16][36]; // y in f32 (update precision)
  __shared__ h1 sA1[16][136], sB1[16][136], sA2[16][136], sB2[16][136];
  __shared__ float sUS[16][36];  // per-(row,l) 0.5*u^2*dt terms

  const int tid = threadIdx.x;
  const int r = tid & 15, c = tid >> 4;  // c in 0..31
  const int b0 = blockIdx.x * 16;
  const int bg = b0 + r;

  for (int i = tid; i < 128 * 96; i += 512) sFW1[i / 96][i % 96] = (h1)fW1[i];
  for (int i = tid; i < 128 * 128; i += 512) sFW2[i >> 7][i & 127] = (h1)fW2[i];
  for (int i = tid; i < 128 * 32; i += 512) sHW1[i >> 5][i & 31] = (h1)hW1[i];
  for (int i = tid; i < 128 * 128; i += 512) sHW2[i >> 7][i & 127] = (h1)hW2[i];
  for (int i = tid; i < 32 * 128; i += 512) {
    sFW3[i >> 7][i & 127] = (h1)fW3[i];
    sHW3[i >> 7][i & 127] = (h1)hW3[i];
  }
  for (int i = tid; i < 128; i += 512) {
    sFB1[i] = fb1[i]; sFB2[i] = fb2[i]; sHB1[i] = hb1[i]; sHB2[i] = hb2[i];
  }
  if (tid < 32) { sFB3[tid] = fb3[tid]; sHB3[tid] = hb3[tid]; }
  __syncthreads();

  // ---- prologue: z0 = mean + exp(logstd)*eps0, from ctx[0] ----
  {
    int rr = tid >> 5, kk = tid & 31;
    *(h2*)&sYC[rr][32 + 2 * kk] =
        *(const h2*)(ctx16 + ((size_t)0 * BB + b0 + rr) * CC + 2 * kk);
  }
  __syncthreads();
  {
    float m0 = qz0b[c], s0 = qz0b[c + 32];
    const float* qm = qz0W + c * 64;
    const float* qs = qz0W + (c + 32) * 64;
#pragma unroll
    for (int k = 0; k < 64; ++k) {
      float cv = (float)sYC[r][32 + k];
      m0 = fmaf(qm[k], cv, m0);
      s0 = fmaf(qs[k], cv, s0);
    }
    float z = fmaf(__expf(s0), eps0[(size_t)bg * LL + c], m0);
    sY32[r][c] = z;
    sYC[r][c] = (h1)z;
  }
  float lqreg = 0.0f;
  __syncthreads();

  for (int t = 0; t < TT - 1; ++t) {
    // A: load ctx[t] (f16, aliased in d_out) for our 16 rows
    {
      int rr = tid >> 5, kk = tid & 31;
      *(h2*)&sYC[rr][32 + 2 * kk] =
          *(const h2*)(ctx16 + ((size_t)t * BB + b0 + rr) * CC + 2 * kk);
    }
    __syncthreads();

    // phase 1: a1 = sp(fW1*[y;c]+fb1), b1 = sp(hW1*y+hb1)
    h2 ycreg[48];
    const h2* ycrow = (const h2*)sYC[r];
#pragma unroll
    for (int k = 0; k < 48; ++k) ycreg[k] = ycrow[k];
#pragma unroll 1
    for (int i = 0; i < 4; ++i) {
      const int j = c + 32 * i;
      const h2* wa = (const h2*)sFW1[j];
      float a0 = 0.f, a1 = 0.f;
#pragma unroll
      for (int k = 0; k < 48; k += 2) {
        a0 = fdot2(wa[k], ycreg[k], a0);
        a1 = fdot2(wa[k + 1], ycreg[k + 1], a1);
      }
      sA1[r][j] = (h1)splus(a0 + a1 + sFB1[j]);
      const h2* wb = (const h2*)sHW1[j];
      float e0 = 0.f, e1 = 0.f;
#pragma unroll
      for (int k = 0; k < 16; k += 2) {
        e0 = fdot2(wb[k], ycreg[k], e0);
        e1 = fdot2(wb[k + 1], ycreg[k + 1], e1);
      }
      sB1[r][j] = (h1)splus(e0 + e1 + sHB1[j]);
    }
    __syncthreads();

    // phase 2: a2 = sp(fW2*a1+fb2), b2 = sp(hW2*b1+hb2)
    {
      h2 areg[64];
      const h2* arow = (const h2*)sA1[r];
#pragma unroll
      for (int k = 0; k < 64; ++k) areg[k] = arow[k];
#pragma unroll 1
      for (int i = 0; i < 4; ++i) {
        const int j = c + 32 * i;
        const h2* w = (const h2*)sFW2[j];
        float a0 = 0.f, a1 = 0.f;
#pragma unroll
        for (int k = 0; k < 64; k += 2) {
          a0 = fdot2(w[k], areg[k], a0);
          a1 = fdot2(w[k + 1], areg[k + 1], a1);
        }
        sA2[r][j] = (h1)splus(a0 + a1 + sFB2[j]);
      }
      const h2* brow = (const h2*)sB1[r];
#pragma unroll
      for (int k = 0; k < 64; ++k) areg[k] = brow[k];
#pragma unroll 1
      for (int i = 0; i < 4; ++i) {
        const int j = c + 32 * i;
        const h2* w = (const h2*)sHW2[j];
        float a0 = 0.f, a1 = 0.f;
#pragma unroll
        for (int k = 0; k < 64; k += 2) {
          a0 = fdot2(w[k], areg[k], a0);
          a1 = fdot2(w[k + 1], areg[k + 1], a1);
        }
        sB2[r][j] = (h1)splus(a0 + a1 + sHB2[j]);
      }
    }
    __syncthreads();

    // phase 3 (l = c): f, hdr, diag g, u, proj write, Euler-Maruyama
    float fv, hv, gv, ynew;
    const float dtv = ts[t + 1] - ts[t];
    {
      h2 areg[64];
      const h2* arow = (const h2*)sA2[r];
#pragma unroll
      for (int k = 0; k < 64; ++k) areg[k] = arow[k];
      const h2* wf = (const h2*)sFW3[c];
      float f0 = 0.f, f1 = 0.f;
#pragma unroll
      for (int k = 0; k < 64; k += 2) {
        f0 = fdot2(wf[k], areg[k], f0);
        f1 = fdot2(wf[k + 1], areg[k + 1], f1);
      }
      fv = f0 + f1 + sFB3[c];
      const h2* brow = (const h2*)sB2[r];
#pragma unroll
      for (int k = 0; k < 64; ++k) areg[k] = brow[k];
      const h2* wh = (const h2*)sHW3[c];
      float g0 = 0.f, g1 = 0.f;
#pragma unroll
      for (int k = 0; k < 64; k += 2) {
        g0 = fdot2(wh[k], areg[k], g0);
        g1 = fdot2(wh[k + 1], areg[k + 1], g1);
      }
      hv = g0 + g1 + sHB3[c];
    }
    {
      float yl = sY32[r][c];
      float ga = 0.f;
      const float4* w1 = (const float4*)(gW1 + c * HH);
      const float4* bb = (const float4*)(gb1 + c * HH);
      const float4* w2 = (const float4*)(gW2 + c * HH);
#pragma unroll 4
      for (int k = 0; k < 32; ++k) {
        float4 a = w1[k], b = bb[k], w = w2[k];
        ga += splus(fmaf(yl, a.x, b.x)) * w.x;
        ga += splus(fmaf(yl, a.y, b.y)) * w.y;
        ga += splus(fmaf(yl, a.z, b.z)) * w.z;
        ga += splus(fmaf(yl, a.w, b.w)) * w.w;
      }
      gv = sigm(ga + gb2[c]);
    }
    float uv = (fv - hv) / gv;
    sUS[r][c] = 0.5f * uv * uv * dtv;
    {
      // xs_hat[t] from PRE-update y (zs[t]); overwrites ctx[t] bytes (already consumed)
      float px = projb[c];
      const float* pw = projW + c * DD;
#pragma unroll
      for (int k = 0; k < 32; ++k) px = fmaf(pw[k], sY32[r][k], px);
      out[(size_t)t * BB * DD + (size_t)bg * DD + c] = px;
    }
    {
      float dW = noise[(size_t)t * BB * LL + (size_t)bg * LL + c];
      ynew = fmaf(fv, dtv, sY32[r][c]) + gv * __fsqrt_rn(dtv) * dW;
    }
    __syncthreads();  // all reads of sY32/sUS-writes settled

    sY32[r][c] = ynew;
    sYC[r][c] = (h1)ynew;
    if (c == 0) {  // deterministic per-row logqp accumulation
      float s = 0.f;
#pragma unroll
      for (int k = 0; k < 32; ++k) s += sUS[r][k];
      lqreg += s;
    }
  }
  __syncthreads();

  // xs_hat[99] from final y; logqp
  {
    float px = projb[c];
    const float* pw = projW + c * DD;
#pragma unroll
    for (int k = 0; k < 32; ++k) px = fmaf(pw[k], sY32[r][k], px);
    out[(size_t)(TT - 1) * BB * DD + (size_t)bg * DD + c] = px;
  }
  if (c == 0) out[(size_t)TT * BB * DD + bg] = lqreg;
}

extern "C" void kernel_launch(void* const* d_in, const int* in_sizes, int n_in,
                              void* d_out, int out_size, void* d_ws,
                              size_t ws_size, hipStream_t stream) {
  const float* xs = (const float*)d_in[0];
  const float* ts = (const float*)d_in[1];
  const float* eps0 = (const float*)d_in[2];
  const float* noise = (const float*)d_in[3];
  const float* Wih = (const float*)d_in[4];
  const float* Whh = (const float*)d_in[5];
  const float* bih = (const float*)d_in[6];
  const float* bhh = (const float*)d_in[7];
  const float* encW = (const float*)d_in[8];
  const float* encb = (const float*)d_in[9];
  const float* qz0W = (const float*)d_in[10];
  const float* qz0b = (const float*)d_in[11];
  const float* fW1 = (const float*)d_in[12];
  const float* fb1 = (const float*)d_in[13];
  const float* fW2 = (const float*)d_in[14];
  const float* fb2 = (const float*)d_in[15];
  const float* fW3 = (const float*)d_in[16];
  const float* fb3 = (const float*)d_in[17];
  const float* hW1 = (const float*)d_in[18];
  const float* hb1 = (const float*)d_in[19];
  const float* hW2 = (const float*)d_in[20];
  const float* hb2 = (const float*)d_in[21];
  const float* hW3 = (const float*)d_in[22];
  const float* hb3 = (const float*)d_in[23];
  const float* gW1 = (const float*)d_in[24];
  const float* gb1 = (const float*)d_in[25];
  const float* gW2 = (const float*)d_in[26];
  const float* gb2 = (const float*)d_in[27];
  const float* projW = (const float*)d_in[28];
  const float* projb = (const float*)d_in[29];
  float* out = (float*)d_out;
  h1* ctx16 = (h1*)d_out;  // ctx[t,b,64] f16 aliases xs_hat[t,b,32] f32 exactly

  k_gru<<<256, 512, 0, stream>>>(xs, Wih, Whh, bih, bhh, encW, encb, ctx16);
  k_sde<<<256, 512, 0, stream>>>(ts, eps0, noise, qz0W, qz0b, fW1, fb1, fW2,
                                 fb2, fW3, fb3, hW1, hb1, hW2, hb2, hW3, hb3,
                                 gW1, gb1, gW2, gb2, projW, projb, ctx16, out);
}

// Round 2
// 2992.335 us; speedup vs baseline: 1.4172x; 1.4172x over previous
//
#include <hip/hip_runtime.h>

// RallyNet: latent-SDE. T=100 steps, B=4096, D=32, L=32, C=64, H=128.
// Parallel over batch only; two persistent kernels loop over time.
// f16 weights+activations in LDS, v_dot2_f32_f16 MACs, f32 accumulation.
// Round 2: spill elimination — all dots stream from LDS with small live sets
// (no areg[64]-style caches), ctx/noise prefetch + double buffers, per-thread
// logqp accumulator. ctx[t,b,:] (f16) staged inside d_out aliasing xs_hat.

#define TT 100
#define BB 4096
#define DD 32
#define LL 32
#define CC 64
#define HH 128

typedef _Float16 h1;
typedef _Float16 h2 __attribute__((ext_vector_type(2)));

__device__ __forceinline__ float fdot2(h2 a, h2 b, float c) {
#if __has_builtin(__builtin_amdgcn_fdot2)
  return __builtin_amdgcn_fdot2(a, b, c, false);
#else
  return c + (float)a[0] * (float)b[0] + (float)a[1] * (float)b[1];
#endif
}

__device__ __forceinline__ float sigm(float x) {
  return 1.0f / (1.0f + __expf(-x));
}
__device__ __forceinline__ float tanh_(float x) {
  float xc = fminf(fmaxf(x, -15.0f), 15.0f);
  float e = __expf(2.0f * xc);
  return (e - 1.0f) / (e + 1.0f);
}
__device__ __forceinline__ float splus(float x) {
  float t = __logf(1.0f + __expf(fminf(x, 15.0f)));
  return x > 15.0f ? x : t;
}

// ---------------- Kernel 1: GRU encoder + Linear(ctx) ----------------
// 256 blocks x 512 threads; block owns 16 batch rows for all 100 steps.
// thread (r = tid&15, c = tid>>4): row r, hidden-unit group {c+32i}.
__global__ __launch_bounds__(512, 2) void k_gru(
    const float* __restrict__ xs, const float* __restrict__ Wih,
    const float* __restrict__ Whh, const float* __restrict__ bih,
    const float* __restrict__ bhh, const float* __restrict__ encW,
    const float* __restrict__ encb, h1* __restrict__ ctx16) {
  __shared__ h1 sWhh[384][136];  // rows 272B: 16B aligned, 2-way banks max
  __shared__ h1 sWih[384][32];   // weight rows broadcast-read; 64B rows ok
  __shared__ h1 sEnc[64][136];
  __shared__ float sBih[384], sBhh[384], sEncB[64];
  __shared__ h1 sH[16][136];
  __shared__ h1 sX[2][16][40];   // 80B rows: 2-way banks

  const int tid = threadIdx.x;
  const int r = tid & 15, c = tid >> 4;  // c in 0..31
  const int b0 = blockIdx.x * 16;

  for (int i = tid; i < 384 * 128; i += 512) sWhh[i >> 7][i & 127] = (h1)Whh[i];
  for (int i = tid; i < 384 * 32; i += 512) sWih[i >> 5][i & 31] = (h1)Wih[i];
  for (int i = tid; i < 64 * 128; i += 512) sEnc[i >> 7][i & 127] = (h1)encW[i];
  for (int i = tid; i < 384; i += 512) { sBih[i] = bih[i]; sBhh[i] = bhh[i]; }
  if (tid < 64) sEncB[tid] = encb[tid];
  for (int i = tid; i < 16 * 136; i += 512) ((h1*)sH)[i] = (h1)0.0f;
  // stage x[0]
  sX[0][tid >> 5][tid & 31] = (h1)xs[(size_t)b0 * DD + tid];
  __syncthreads();

  for (int t = 0; t < TT; ++t) {
    const int xb = t & 1;
    // prefetch x[t+1] (clamped; load overlaps gate compute)
    const int tn = (t + 1 < TT) ? (t + 1) : (TT - 1);
    const float xnext = xs[(size_t)tn * BB * DD + (size_t)b0 * DD + tid];

    const h2* hr = (const h2*)sH[r];
    const h2* xr = (const h2*)sX[xb][r];
    float hnew[4];
#pragma unroll 1
    for (int i = 0; i < 4; ++i) {
      const int m = c + 32 * i;
      const h2* wr = (const h2*)sWhh[m];
      const h2* wz = (const h2*)sWhh[128 + m];
      const h2* wn = (const h2*)sWhh[256 + m];
      float rr0 = 0.f, rr1 = 0.f, zz0 = 0.f, zz1 = 0.f, nn0 = 0.f, nn1 = 0.f;
#pragma unroll 4
      for (int k = 0; k < 64; k += 2) {
        h2 a0 = hr[k], a1 = hr[k + 1];
        rr0 = fdot2(wr[k], a0, rr0);
        rr1 = fdot2(wr[k + 1], a1, rr1);
        zz0 = fdot2(wz[k], a0, zz0);
        zz1 = fdot2(wz[k + 1], a1, zz1);
        nn0 = fdot2(wn[k], a0, nn0);
        nn1 = fdot2(wn[k + 1], a1, nn1);
      }
      const h2* ur = (const h2*)sWih[m];
      const h2* uz = (const h2*)sWih[128 + m];
      const h2* un = (const h2*)sWih[256 + m];
      float xr0 = 0.f, xz0 = 0.f, xn0 = 0.f;
#pragma unroll 4
      for (int k = 0; k < 16; ++k) {
        h2 x0 = xr[k];
        xr0 = fdot2(ur[k], x0, xr0);
        xz0 = fdot2(uz[k], x0, xz0);
        xn0 = fdot2(un[k], x0, xn0);
      }
      float air = xr0 + sBih[m], ahr = rr0 + rr1 + sBhh[m];
      float aiz = xz0 + sBih[128 + m], ahz = zz0 + zz1 + sBhh[128 + m];
      float ain = xn0 + sBih[256 + m], ahn = nn0 + nn1 + sBhh[256 + m];
      float rg = sigm(air + ahr);
      float zg = sigm(aiz + ahz);
      float ng = tanh_(ain + rg * ahn);
      hnew[i] = (1.0f - zg) * ng + zg * (float)sH[r][m];
    }
    // stage x[t+1] (last reads of this buffer were 2 barriers ago)
    sX[xb ^ 1][tid >> 5][tid & 31] = (h1)xnext;
    __syncthreads();  // all reads of sH done
#pragma unroll
    for (int i = 0; i < 4; ++i) sH[r][c + 32 * i] = (h1)hnew[i];
    __syncthreads();  // h fully updated

    // encoder: ctx cols {2c, 2c+1} from updated h (streamed)
    {
      const int c0 = 2 * c, c1 = 2 * c + 1;
      const h2* w0 = (const h2*)sEnc[c0];
      const h2* w1 = (const h2*)sEnc[c1];
      float e00 = 0.f, e01 = 0.f, e10 = 0.f, e11 = 0.f;
#pragma unroll 4
      for (int k = 0; k < 64; k += 2) {
        h2 a0 = hr[k], a1 = hr[k + 1];
        e00 = fdot2(w0[k], a0, e00);
        e01 = fdot2(w0[k + 1], a1, e01);
        e10 = fdot2(w1[k], a0, e10);
        e11 = fdot2(w1[k + 1], a1, e11);
      }
      h2 o;
      o[0] = (h1)(e00 + e01 + sEncB[c0]);
      o[1] = (h1)(e10 + e11 + sEncB[c1]);
      *(h2*)(ctx16 + ((size_t)t * BB + b0 + r) * CC + c0) = o;
    }
  }
}

// ---------------- Kernel 2: posterior z0 + SDE scan + projection ----------------
// 256 blocks x 512 threads; thread (r = tid&15, c = tid>>4): row r, col group c.
__global__ __launch_bounds__(512, 2) void k_sde(
    const float* __restrict__ ts, const float* __restrict__ eps0,
    const float* __restrict__ noise, const float* __restrict__ qz0W,
    const float* __restrict__ qz0b, const float* __restrict__ fW1,
    const float* __restrict__ fb1, const float* __restrict__ fW2,
    const float* __restrict__ fb2, const float* __restrict__ fW3,
    const float* __restrict__ fb3, const float* __restrict__ hW1,
    const float* __restrict__ hb1, const float* __restrict__ hW2,
    const float* __restrict__ hb2, const float* __restrict__ hW3,
    const float* __restrict__ hb3, const float* __restrict__ gW1,
    const float* __restrict__ gb1, const float* __restrict__ gW2,
    const float* __restrict__ gb2, const float* __restrict__ projW,
    const float* __restrict__ projb, const h1* __restrict__ ctx16,
    float* __restrict__ out) {
  __shared__ h1 sFW1[128][104];  // [j][0..31]=y part, [32..95]=ctx part; 208B rows
  __shared__ h1 sHW1[128][40];
  __shared__ h1 sFW2[128][136];
  __shared__ h1 sHW2[128][136];
  __shared__ h1 sFW3[32][136];
  __shared__ h1 sHW3[32][136];
  __shared__ float sFB1[128], sFB2[128], sFB3[32];
  __shared__ float sHB1[128], sHB2[128], sHB3[32];
  __shared__ h1 sY16[2][16][40];   // y in f16 (80B rows)
  __shared__ h1 sC[2][16][72];     // ctx in f16 (144B rows, 16B aligned)
  __shared__ float sY32[2][16][36];  // y in f32 (144B rows)
  __shared__ h1 sA1[16][136], sB1[16][136], sA2[16][136], sB2[16][136];
  __shared__ float sUS[16][36];

  const int tid = threadIdx.x;
  const int r = tid & 15, c = tid >> 4;  // c in 0..31
  const int b0 = blockIdx.x * 16;
  const int bg = b0 + r;
  const int rr = tid >> 5, kk = tid & 31;  // ctx staging map

  for (int i = tid; i < 128 * 96; i += 512) sFW1[i / 96][i % 96] = (h1)fW1[i];
  for (int i = tid; i < 128 * 32; i += 512) sHW1[i >> 5][i & 31] = (h1)hW1[i];
  for (int i = tid; i < 128 * 128; i += 512) sFW2[i >> 7][i & 127] = (h1)fW2[i];
  for (int i = tid; i < 128 * 128; i += 512) sHW2[i >> 7][i & 127] = (h1)hW2[i];
  for (int i = tid; i < 32 * 128; i += 512) {
    sFW3[i >> 7][i & 127] = (h1)fW3[i];
    sHW3[i >> 7][i & 127] = (h1)hW3[i];
  }
  for (int i = tid; i < 128; i += 512) {
    sFB1[i] = fb1[i]; sFB2[i] = fb2[i]; sHB1[i] = hb1[i]; sHB2[i] = hb2[i];
  }
  if (tid < 32) { sFB3[tid] = fb3[tid]; sHB3[tid] = hb3[tid]; }
  // stage ctx[0]
  *(h2*)&sC[0][rr][2 * kk] =
      *(const h2*)(ctx16 + ((size_t)(b0 + rr)) * CC + 2 * kk);
  __syncthreads();

  // ---- prologue: z0 = mean + exp(logstd)*eps0 ----
  {
    float m0 = qz0b[c], s0 = qz0b[c + 32];
    const float* qm = qz0W + c * 64;
    const float* qs = qz0W + (c + 32) * 64;
#pragma unroll 4
    for (int k = 0; k < 64; ++k) {
      float cv = (float)sC[0][r][k];
      m0 = fmaf(qm[k], cv, m0);
      s0 = fmaf(qs[k], cv, s0);
    }
    float z = fmaf(__expf(s0), eps0[(size_t)bg * LL + c], m0);
    sY32[0][r][c] = z;
    sY16[0][r][c] = (h1)z;
  }
  float lqp = 0.0f;
  __syncthreads();

  for (int t = 0; t < TT - 1; ++t) {
    const int cb = t & 1;
    // prefetch ctx[t+1] + noise[t] (loads overlap phase-1 compute)
    const h2 cpre =
        *(const h2*)(ctx16 + ((size_t)(t + 1) * BB + b0 + rr) * CC + 2 * kk);
    const float dW = noise[(size_t)t * BB * LL + (size_t)bg * LL + c];
    const float dtv = ts[t + 1] - ts[t];

    // ---- phase 1: a1 = sp(fW1*[y;c]+fb1), b1 = sp(hW1*y+hb1) ----
    {
      const h2* yr = (const h2*)sY16[cb][r];
      const h2* cr = (const h2*)sC[cb][r];
#pragma unroll 1
      for (int i = 0; i < 4; ++i) {
        const int j = c + 32 * i;
        const h2* wf = (const h2*)sFW1[j];
        const h2* wh = (const h2*)sHW1[j];
        float f0 = 0.f, f1 = 0.f, g0 = 0.f, g1 = 0.f;
#pragma unroll 4
        for (int k = 0; k < 16; k += 2) {
          h2 y0 = yr[k], y1 = yr[k + 1];
          f0 = fdot2(wf[k], y0, f0);
          f1 = fdot2(wf[k + 1], y1, f1);
          g0 = fdot2(wh[k], y0, g0);
          g1 = fdot2(wh[k + 1], y1, g1);
        }
#pragma unroll 4
        for (int k = 0; k < 32; k += 2) {
          h2 c0 = cr[k], c1 = cr[k + 1];
          f0 = fdot2(wf[16 + k], c0, f0);
          f1 = fdot2(wf[17 + k], c1, f1);
        }
        sA1[r][j] = (h1)splus(f0 + f1 + sFB1[j]);
        sB1[r][j] = (h1)splus(g0 + g1 + sHB1[j]);
      }
    }
    // stage prefetched ctx for t+1 (buffer last read at p1 of t-1)
    *(h2*)&sC[cb ^ 1][rr][2 * kk] = cpre;
    __syncthreads();

    // ---- phase 2: a2 = sp(fW2*a1+fb2), b2 = sp(hW2*b1+hb2) ----
    {
      const h2* ar = (const h2*)sA1[r];
      const h2* br = (const h2*)sB1[r];
#pragma unroll 1
      for (int i = 0; i < 4; ++i) {
        const int j = c + 32 * i;
        const h2* wa = (const h2*)sFW2[j];
        const h2* wb = (const h2*)sHW2[j];
        float p0 = 0.f, p1 = 0.f, q0 = 0.f, q1 = 0.f;
#pragma unroll 4
        for (int k = 0; k < 64; k += 2) {
          p0 = fdot2(wa[k], ar[k], p0);
          p1 = fdot2(wa[k + 1], ar[k + 1], p1);
          q0 = fdot2(wb[k], br[k], q0);
          q1 = fdot2(wb[k + 1], br[k + 1], q1);
        }
        sA2[r][j] = (h1)splus(p0 + p1 + sFB2[j]);
        sB2[r][j] = (h1)splus(q0 + q1 + sHB2[j]);
      }
    }
    __syncthreads();

    // ---- phase 3: f, hdr, diag g, u, proj, Euler-Maruyama ----
    float fv, hv;
    {
      const h2* ar = (const h2*)sA2[r];
      const h2* wf = (const h2*)sFW3[c];
      float f0 = 0.f, f1 = 0.f;
#pragma unroll 4
      for (int k = 0; k < 64; k += 2) {
        f0 = fdot2(wf[k], ar[k], f0);
        f1 = fdot2(wf[k + 1], ar[k + 1], f1);
      }
      fv = f0 + f1 + sFB3[c];
      const h2* br = (const h2*)sB2[r];
      const h2* wh = (const h2*)sHW3[c];
      float g0 = 0.f, g1 = 0.f;
#pragma unroll 4
      for (int k = 0; k < 64; k += 2) {
        g0 = fdot2(wh[k], br[k], g0);
        g1 = fdot2(wh[k + 1], br[k + 1], g1);
      }
      hv = g0 + g1 + sHB3[c];
    }
    const float yl = sY32[cb][r][c];
    float gv;
    {
      float ga = 0.f;
      const float4* w1 = (const float4*)(gW1 + c * HH);
      const float4* bb4 = (const float4*)(gb1 + c * HH);
      const float4* w2 = (const float4*)(gW2 + c * HH);
#pragma unroll 2
      for (int k = 0; k < 32; ++k) {
        float4 a = w1[k], b = bb4[k], w = w2[k];
        ga += splus(fmaf(yl, a.x, b.x)) * w.x;
        ga += splus(fmaf(yl, a.y, b.y)) * w.y;
        ga += splus(fmaf(yl, a.z, b.z)) * w.z;
        ga += splus(fmaf(yl, a.w, b.w)) * w.w;
      }
      gv = sigm(ga + gb2[c]);
    }
    const float uv = (fv - hv) / gv;
    lqp += 0.5f * uv * uv * dtv;
    {
      // xs_hat[t] from pre-update y (overwrites consumed ctx[t] bytes)
      float px = projb[c];
      const float4* pw4 = (const float4*)(projW + c * DD);
      const float4* ya4 = (const float4*)sY32[cb][r];
#pragma unroll
      for (int k = 0; k < 8; ++k) {
        float4 w = pw4[k], a = ya4[k];
        px += w.x * a.x + w.y * a.y + w.z * a.z + w.w * a.w;
      }
      out[(size_t)t * BB * DD + (size_t)bg * DD + c] = px;
    }
    const float ynew = fmaf(fv, dtv, yl) + gv * __fsqrt_rn(dtv) * dW;
    sY32[cb ^ 1][r][c] = ynew;
    sY16[cb ^ 1][r][c] = (h1)ynew;
    __syncthreads();
  }

  // xs_hat[99] from final y; logqp reduce
  {
    const int fb = (TT - 1) & 1;
    float px = projb[c];
    const float4* pw4 = (const float4*)(projW + c * DD);
    const float4* ya4 = (const float4*)sY32[fb][r];
#pragma unroll
    for (int k = 0; k < 8; ++k) {
      float4 w = pw4[k], a = ya4[k];
      px += w.x * a.x + w.y * a.y + w.z * a.z + w.w * a.w;
    }
    out[(size_t)(TT - 1) * BB * DD + (size_t)bg * DD + c] = px;
  }
  sUS[r][c] = lqp;
  __syncthreads();
  if (c == 0) {
    float s = 0.f;
#pragma unroll
    for (int k = 0; k < 32; ++k) s += sUS[r][k];
    out[(size_t)TT * BB * DD + bg] = s;
  }
}

extern "C" void kernel_launch(void* const* d_in, const int* in_sizes, int n_in,
                              void* d_out, int out_size, void* d_ws,
                              size_t ws_size, hipStream_t stream) {
  const float* xs = (const float*)d_in[0];
  const float* ts = (const float*)d_in[1];
  const float* eps0 = (const float*)d_in[2];
  const float* noise = (const float*)d_in[3];
  const float* Wih = (const float*)d_in[4];
  const float* Whh = (const float*)d_in[5];
  const float* bih = (const float*)d_in[6];
  const float* bhh = (const float*)d_in[7];
  const float* encW = (const float*)d_in[8];
  const float* encb = (const float*)d_in[9];
  const float* qz0W = (const float*)d_in[10];
  const float* qz0b = (const float*)d_in[11];
  const float* fW1 = (const float*)d_in[12];
  const float* fb1 = (const float*)d_in[13];
  const float* fW2 = (const float*)d_in[14];
  const float* fb2 = (const float*)d_in[15];
  const float* fW3 = (const float*)d_in[16];
  const float* fb3 = (const float*)d_in[17];
  const float* hW1 = (const float*)d_in[18];
  const float* hb1 = (const float*)d_in[19];
  const float* hW2 = (const float*)d_in[20];
  const float* hb2 = (const float*)d_in[21];
  const float* hW3 = (const float*)d_in[22];
  const float* hb3 = (const float*)d_in[23];
  const float* gW1 = (const float*)d_in[24];
  const float* gb1 = (const float*)d_in[25];
  const float* gW2 = (const float*)d_in[26];
  const float* gb2 = (const float*)d_in[27];
  const float* projW = (const float*)d_in[28];
  const float* projb = (const float*)d_in[29];
  float* out = (float*)d_out;
  h1* ctx16 = (h1*)d_out;  // ctx[t,b,64] f16 aliases xs_hat[t,b,32] f32 exactly

  k_gru<<<256, 512, 0, stream>>>(xs, Wih, Whh, bih, bhh, encW, encb, ctx16);
  k_sde<<<256, 512, 0, stream>>>(ts, eps0, noise, qz0W, qz0b, fW1, fb1, fW2,
                                 fb2, fW3, fb3, hW1, hb1, hW2, hb2, hW3, hb3,
                                 gW1, gb1, gW2, gb2, projW, projb, ctx16, out);
}

// Round 3
// 572.128 us; speedup vs baseline: 7.4123x; 5.2302x over previous
//
#include <hip/hip_runtime.h>

// RallyNet latent-SDE, round 3: MFMA 16x16x32 f16 for all dense layers,
// weights register-resident as B-fragments, activations ping-pong in LDS
// (f16, D-fragment writes / A-fragment b128 reads), diag-g net replaced by
// per-l piecewise-linear LDS table (built once per block).
// ctx[t,b,:] (f16) aliases xs_hat[t,b,:] (f32) inside d_out: consumed at
// step t, overwritten by the projection at step t.
// T=100, B=4096, D=32, L=32, C=64, H=128. 256 blocks x 512 threads.

#define TT 100
#define BB 4096
#define DD 32
#define LL 32
#define CC 64
#define HH 128

typedef _Float16 h1;
typedef _Float16 h2 __attribute__((ext_vector_type(2)));
typedef _Float16 f16x8 __attribute__((ext_vector_type(8)));
typedef float f32x4 __attribute__((ext_vector_type(4)));

#define MFMA(a, b, c) __builtin_amdgcn_mfma_f32_16x16x32_f16(a, b, c, 0, 0, 0)

__device__ __forceinline__ float sigm(float x) {
  return 1.0f / (1.0f + __expf(-x));
}
__device__ __forceinline__ float tanh_(float x) {
  float xc = fminf(fmaxf(x, -15.0f), 15.0f);
  float e = __expf(2.0f * xc);
  return (e - 1.0f) / (e + 1.0f);
}
__device__ __forceinline__ float splus(float x) {
  float t = __logf(1.0f + __expf(fminf(x, 15.0f)));
  return x > 15.0f ? x : t;
}

// B-fragment of row-major W[N][K] at tile (n0, k0):
// lane l, reg j  ->  B[k0 + (l>>4)*8 + j][n0 + (l&15)] = W[n0+(l&15)][k0+(l>>4)*8+j]
__device__ __forceinline__ f16x8 bfrag(const float* __restrict__ W, int K,
                                       int n0, int k0, int lane) {
  const float* p = W + (size_t)(n0 + (lane & 15)) * K + k0 + ((lane >> 4) << 3);
  f16x8 r;
#pragma unroll
  for (int j = 0; j < 8; ++j) r[j] = (h1)p[j];
  return r;
}

// A-fragment from LDS tile (row-major, ld f16 elems/row, 16B-aligned rows):
// lane l reads A[l&15][k0 + (l>>4)*8 .. +7] as one b128.
__device__ __forceinline__ f16x8 afrag(const h1* base, int ld, int k0,
                                       int lane) {
  return *(const f16x8*)(base + (size_t)(lane & 15) * ld + k0 +
                         ((lane >> 4) << 3));
}

// ---------------- Kernel 1: GRU encoder + Linear(ctx) ----------------
__global__ __launch_bounds__(512, 2) void k_gru(
    const float* __restrict__ xs, const float* __restrict__ Wih,
    const float* __restrict__ Whh, const float* __restrict__ bih,
    const float* __restrict__ bhh, const float* __restrict__ encW,
    const float* __restrict__ encb, h1* __restrict__ ctx16) {
  __shared__ alignas(16) h1 sH[2][16][136];  // 272B rows
  __shared__ alignas(16) h1 sX[2][16][40];   // 80B rows
  __shared__ alignas(16) h1 sCtx[16][64];    // 128B rows
  __shared__ float sBih[384], sBhh[384], sEncB[64];

  const int tid = threadIdx.x;
  const int lane = tid & 63, w = tid >> 6;  // wave 0..7 owns units 16w..16w+15
  const int b0 = blockIdx.x * 16;
  const int coln = lane & 15, row4 = (lane >> 4) << 2;

  for (int i = tid; i < 384; i += 512) { sBih[i] = bih[i]; sBhh[i] = bhh[i]; }
  if (tid < 64) sEncB[tid] = encb[tid];

  // register-resident weight fragments
  f16x8 wIH[3], wHH[3][4], wE[4];
#pragma unroll
  for (int g = 0; g < 3; ++g) {
    wIH[g] = bfrag(Wih, DD, 128 * g + 16 * w, 0, lane);
#pragma unroll
    for (int kt = 0; kt < 4; ++kt)
      wHH[g][kt] = bfrag(Whh, HH, 128 * g + 16 * w, 32 * kt, lane);
  }
  if (w >= 4) {
#pragma unroll
    for (int kt = 0; kt < 4; ++kt)
      wE[kt] = bfrag(encW, HH, 16 * (w - 4), 32 * kt, lane);
  }

  for (int i = tid; i < 2 * 16 * 136; i += 512) (&sH[0][0][0])[i] = (h1)0.0f;
  sX[0][tid >> 5][tid & 31] = (h1)xs[(size_t)b0 * DD + tid];
  float hold[4] = {0.f, 0.f, 0.f, 0.f};
  __syncthreads();

  const int m = 16 * w + coln;
  const float b_r = sBih[m] + sBhh[m];
  const float b_z = sBih[128 + m] + sBhh[128 + m];
  const float b_ni = sBih[256 + m];
  const float b_nh = sBhh[256 + m];
  const float bE = (w >= 4) ? sEncB[16 * (w - 4) + coln] : 0.f;

  for (int t = 0; t < TT; ++t) {
    const int cur = t & 1;
    float xn = 0.f;
    if (t + 1 < TT) xn = xs[(size_t)(t + 1) * BB * DD + (size_t)b0 * DD + tid];

    // gates: acc = x@Wih_g.T + h@Whh_g.T (r,z fused; n kept split for r*hn)
    f16x8 ax = afrag(&sX[cur][0][0], 40, 0, lane);
    f32x4 aR{0, 0, 0, 0}, aZ{0, 0, 0, 0}, aNI{0, 0, 0, 0}, aNH{0, 0, 0, 0};
    aR = MFMA(ax, wIH[0], aR);
    aZ = MFMA(ax, wIH[1], aZ);
    aNI = MFMA(ax, wIH[2], aNI);
#pragma unroll
    for (int kt = 0; kt < 4; ++kt) {
      f16x8 ah = afrag(&sH[cur][0][0], 136, 32 * kt, lane);
      aR = MFMA(ah, wHH[0][kt], aR);
      aZ = MFMA(ah, wHH[1][kt], aZ);
      aNH = MFMA(ah, wHH[2][kt], aNH);
    }
#pragma unroll
    for (int j = 0; j < 4; ++j) {
      float rg = sigm(aR[j] + b_r);
      float zg = sigm(aZ[j] + b_z);
      float ng = tanh_(aNI[j] + b_ni + rg * (aNH[j] + b_nh));
      float hn = (1.0f - zg) * ng + zg * hold[j];
      hold[j] = hn;  // pre-update h for next step kept in f32 regs (D-layout)
      sH[cur ^ 1][row4 + j][m] = (h1)hn;
    }
    sX[cur ^ 1][tid >> 5][tid & 31] = (h1)xn;
    __syncthreads();

    // encoder (waves 4..7): ctx tile from the UPDATED h
    if (w >= 4) {
      f32x4 aE{0, 0, 0, 0};
#pragma unroll
      for (int kt = 0; kt < 4; ++kt)
        aE = MFMA(afrag(&sH[cur ^ 1][0][0], 136, 32 * kt, lane), wE[kt], aE);
#pragma unroll
      for (int j = 0; j < 4; ++j)
        sCtx[row4 + j][16 * (w - 4) + coln] = (h1)(aE[j] + bE);
    }
    __syncthreads();
    // coalesced ctx store: 512 threads x 4B = full 16x64 f16 tile
    *(h2*)(ctx16 + ((size_t)t * BB + b0 + (tid >> 5)) * CC + 2 * (tid & 31)) =
        *(const h2*)&sCtx[tid >> 5][2 * (tid & 31)];
  }
}

// ---------------- Kernel 2: z0 + SDE scan + projection ----------------
__global__ __launch_bounds__(512, 2) void k_sde(
    const float* __restrict__ ts, const float* __restrict__ eps0,
    const float* __restrict__ noise, const float* __restrict__ qz0W,
    const float* __restrict__ qz0b, const float* __restrict__ fW1,
    const float* __restrict__ fb1, const float* __restrict__ fW2,
    const float* __restrict__ fb2, const float* __restrict__ fW3,
    const float* __restrict__ fb3, const float* __restrict__ hW1,
    const float* __restrict__ hb1, const float* __restrict__ hW2,
    const float* __restrict__ hb2, const float* __restrict__ hW3,
    const float* __restrict__ hb3, const float* __restrict__ gW1,
    const float* __restrict__ gb1, const float* __restrict__ gW2,
    const float* __restrict__ gb2, const float* __restrict__ projW,
    const float* __restrict__ projb, const h1* __restrict__ ctx16,
    float* __restrict__ out) {
  __shared__ alignas(16) h1 sYC[2][16][104];  // [y(0..31)|ctx(32..95)], 208B rows
  __shared__ alignas(16) h1 sA1[16][136], sB1[16][136];
  __shared__ alignas(16) h1 sA2[16][136], sB2[16][136];
  __shared__ float sFv[16][33], sHv[16][33];
  __shared__ float sG[32][260];  // PWL table: 257 knots over y in [-12,12]
  __shared__ float sFB1[128], sHB1[128], sFB2[128], sHB2[128];
  __shared__ float sFB3[32], sHB3[32], sPjB[32];

  const int tid = threadIdx.x;
  const int lane = tid & 63, w = tid >> 6;
  const int b0 = blockIdx.x * 16;
  const int r = tid >> 5, c = tid & 31;  // per-thread (batch row, latent dim)
  const int bg = b0 + r;
  const int coln = lane & 15, row4 = (lane >> 4) << 2;

  for (int i = tid; i < 128; i += 512) {
    sFB1[i] = fb1[i]; sHB1[i] = hb1[i]; sFB2[i] = fb2[i]; sHB2[i] = hb2[i];
  }
  if (tid < 32) { sFB3[tid] = fb3[tid]; sHB3[tid] = hb3[tid]; sPjB[tid] = projb[tid]; }

  // register-resident weight fragments
  f16x8 wF1[3], wH1v, wF2[4], wH2[4], wP3[4], wPj;
#pragma unroll
  for (int kt = 0; kt < 3; ++kt) wF1[kt] = bfrag(fW1, 96, 16 * w, 32 * kt, lane);
  wH1v = bfrag(hW1, 32, 16 * w, 0, lane);
#pragma unroll
  for (int kt = 0; kt < 4; ++kt) {
    wF2[kt] = bfrag(fW2, HH, 16 * w, 32 * kt, lane);
    wH2[kt] = bfrag(hW2, HH, 16 * w, 32 * kt, lane);
  }
  if (w < 2) {
#pragma unroll
    for (int kt = 0; kt < 4; ++kt) wP3[kt] = bfrag(fW3, HH, 16 * w, 32 * kt, lane);
  } else if (w < 4) {
#pragma unroll
    for (int kt = 0; kt < 4; ++kt) wP3[kt] = bfrag(hW3, HH, 16 * (w - 2), 32 * kt, lane);
  } else if (w < 6) {
    wPj = bfrag(projW, LL, 16 * (w - 4), 0, lane);
  }

  // build PWL g-table: wave handles latent dim l, lanes = knot index
  for (int l = w; l < 32; l += 8) {
    const float* w1 = gW1 + l * HH;
    const float* bb = gb1 + l * HH;
    const float* w2 = gW2 + l * HH;
    const float b2v = gb2[l];
    for (int e0 = 0; e0 < 257; e0 += 64) {
      const int e = e0 + lane;
      const float yv = -12.f + (float)e * (24.f / 256.f);
      float a = 0.f;
#pragma unroll 4
      for (int hh = 0; hh < HH; ++hh)
        a = fmaf(splus(fmaf(yv, w1[hh], bb[hh])), w2[hh], a);
      if (e < 257) sG[l][e] = sigm(a + b2v);
    }
  }

  // stage ctx[0]
  *(h2*)&sYC[0][r][32 + 2 * c] =
      *(const h2*)(ctx16 + (size_t)(b0 + r) * CC + 2 * c);
  __syncthreads();

  // z0 = mean + exp(logstd)*eps0 (per-thread scalar, one-time)
  float yreg;
  {
    float m0 = qz0b[c], s0 = qz0b[32 + c];
    const float* qm = qz0W + c * 64;
    const float* qs = qz0W + (32 + c) * 64;
#pragma unroll 4
    for (int k = 0; k < 64; ++k) {
      float cv = (float)sYC[0][r][32 + k];
      m0 = fmaf(qm[k], cv, m0);
      s0 = fmaf(qs[k], cv, s0);
    }
    yreg = fmaf(__expf(s0), eps0[(size_t)bg * LL + c], m0);
  }
  sYC[0][r][c] = (h1)yreg;
  float lqp = 0.f;
  __syncthreads();

  for (int t = 0; t < TT - 1; ++t) {
    const int cur = t & 1;
    // prefetch next ctx + this step's noise/dt
    const h2 cpre =
        *(const h2*)(ctx16 + ((size_t)(t + 1) * BB + b0 + r) * CC + 2 * c);
    const float dW = noise[((size_t)t * BB + bg) * LL + c];
    const float dtv = ts[t + 1] - ts[t];
    const float sqdt = __fsqrt_rn(dtv);

    // P1: a1 = sp(fW1*[y;c]+fb1)  b1 = sp(hW1*y+hb1); wave w -> units 16w..
    {
      f16x8 aY = afrag(&sYC[cur][0][0], 104, 0, lane);
      f16x8 aC0 = afrag(&sYC[cur][0][0], 104, 32, lane);
      f16x8 aC1 = afrag(&sYC[cur][0][0], 104, 64, lane);
      f32x4 aF{0, 0, 0, 0}, aH{0, 0, 0, 0};
      aF = MFMA(aY, wF1[0], aF);
      aF = MFMA(aC0, wF1[1], aF);
      aF = MFMA(aC1, wF1[2], aF);
      aH = MFMA(aY, wH1v, aH);
      const int cc = 16 * w + coln;
      const float bF = sFB1[cc], bH = sHB1[cc];
#pragma unroll
      for (int j = 0; j < 4; ++j) {
        sA1[row4 + j][cc] = (h1)splus(aF[j] + bF);
        sB1[row4 + j][cc] = (h1)splus(aH[j] + bH);
      }
    }
    __syncthreads();

    // P2: a2 = sp(fW2*a1+fb2)  b2 = sp(hW2*b1+hb2)
    {
      f32x4 aF{0, 0, 0, 0}, aH{0, 0, 0, 0};
#pragma unroll
      for (int kt = 0; kt < 4; ++kt) {
        aF = MFMA(afrag(&sA1[0][0], 136, 32 * kt, lane), wF2[kt], aF);
        aH = MFMA(afrag(&sB1[0][0], 136, 32 * kt, lane), wH2[kt], aH);
      }
      const int cc = 16 * w + coln;
      const float bF = sFB2[cc], bH = sHB2[cc];
#pragma unroll
      for (int j = 0; j < 4; ++j) {
        sA2[row4 + j][cc] = (h1)splus(aF[j] + bF);
        sB2[row4 + j][cc] = (h1)splus(aH[j] + bH);
      }
    }
    __syncthreads();

    // P3: f (waves 0-1), hdr (2-3), projection of zs[t] (4-5)
    if (w < 2) {
      f32x4 acc{0, 0, 0, 0};
#pragma unroll
      for (int kt = 0; kt < 4; ++kt)
        acc = MFMA(afrag(&sA2[0][0], 136, 32 * kt, lane), wP3[kt], acc);
      const int cc = 16 * w + coln;
#pragma unroll
      for (int j = 0; j < 4; ++j) sFv[row4 + j][cc] = acc[j] + sFB3[cc];
    } else if (w < 4) {
      f32x4 acc{0, 0, 0, 0};
#pragma unroll
      for (int kt = 0; kt < 4; ++kt)
        acc = MFMA(afrag(&sB2[0][0], 136, 32 * kt, lane), wP3[kt], acc);
      const int cc = 16 * (w - 2) + coln;
#pragma unroll
      for (int j = 0; j < 4; ++j) sHv[row4 + j][cc] = acc[j] + sHB3[cc];
    } else if (w < 6) {
      f32x4 acc{0, 0, 0, 0};
      acc = MFMA(afrag(&sYC[cur][0][0], 104, 0, lane), wPj, acc);
      const int cc = 16 * (w - 4) + coln;
#pragma unroll
      for (int j = 0; j < 4; ++j)
        out[((size_t)t * BB + b0 + row4 + j) * DD + cc] = acc[j] + sPjB[cc];
    }
    // stage prefetched ctx[t+1]
    *(h2*)&sYC[cur ^ 1][r][32 + 2 * c] = cpre;
    __syncthreads();

    // update: u = (f-h)/g, logqp accum, Euler-Maruyama
    {
      const float f = sFv[r][c], hd = sHv[r][c];
      float p = (yreg + 12.f) * (256.f / 24.f);
      p = fminf(fmaxf(p, 0.f), 255.999f);
      const int i = (int)p;
      const float fr = p - (float)i;
      const float g0 = sG[c][i], g1 = sG[c][i + 1];
      const float gv = fmaf(g1 - g0, fr, g0);
      const float uv = (f - hd) / gv;
      lqp = fmaf(0.5f * uv * uv, dtv, lqp);
      yreg = fmaf(f, dtv, yreg) + gv * sqdt * dW;
      sYC[cur ^ 1][r][c] = (h1)yreg;
    }
    __syncthreads();
  }

  // final projection xs_hat[99] from z_99; logqp reduce
  {
    const int fbuf = (TT - 1) & 1;
    if (w >= 4 && w < 6) {
      f32x4 acc{0, 0, 0, 0};
      acc = MFMA(afrag(&sYC[fbuf][0][0], 104, 0, lane), wPj, acc);
      const int cc = 16 * (w - 4) + coln;
#pragma unroll
      for (int j = 0; j < 4; ++j)
        out[((size_t)(TT - 1) * BB + b0 + row4 + j) * DD + cc] =
            acc[j] + sPjB[cc];
    }
    sFv[r][c] = lqp;
    __syncthreads();
    if (tid < 16) {
      float s = 0.f;
#pragma unroll
      for (int k = 0; k < 32; ++k) s += sFv[tid][k];
      out[(size_t)TT * BB * DD + b0 + tid] = s;
    }
  }
}

extern "C" void kernel_launch(void* const* d_in, const int* in_sizes, int n_in,
                              void* d_out, int out_size, void* d_ws,
                              size_t ws_size, hipStream_t stream) {
  const float* xs = (const float*)d_in[0];
  const float* ts = (const float*)d_in[1];
  const float* eps0 = (const float*)d_in[2];
  const float* noise = (const float*)d_in[3];
  const float* Wih = (const float*)d_in[4];
  const float* Whh = (const float*)d_in[5];
  const float* bih = (const float*)d_in[6];
  const float* bhh = (const float*)d_in[7];
  const float* encW = (const float*)d_in[8];
  const float* encb = (const float*)d_in[9];
  const float* qz0W = (const float*)d_in[10];
  const float* qz0b = (const float*)d_in[11];
  const float* fW1 = (const float*)d_in[12];
  const float* fb1 = (const float*)d_in[13];
  const float* fW2 = (const float*)d_in[14];
  const float* fb2 = (const float*)d_in[15];
  const float* fW3 = (const float*)d_in[16];
  const float* fb3 = (const float*)d_in[17];
  const float* hW1 = (const float*)d_in[18];
  const float* hb1 = (const float*)d_in[19];
  const float* hW2 = (const float*)d_in[20];
  const float* hb2 = (const float*)d_in[21];
  const float* hW3 = (const float*)d_in[22];
  const float* hb3 = (const float*)d_in[23];
  const float* gW1 = (const float*)d_in[24];
  const float* gb1 = (const float*)d_in[25];
  const float* gW2 = (const float*)d_in[26];
  const float* gb2 = (const float*)d_in[27];
  const float* projW = (const float*)d_in[28];
  const float* projb = (const float*)d_in[29];
  float* out = (float*)d_out;
  h1* ctx16 = (h1*)d_out;  // ctx[t,b,64] f16 aliases xs_hat[t,b,32] f32

  k_gru<<<256, 512, 0, stream>>>(xs, Wih, Whh, bih, bhh, encW, encb, ctx16);
  k_sde<<<256, 512, 0, stream>>>(ts, eps0, noise, qz0W, qz0b, fW1, fb1, fW2,
                                 fb2, fW3, fb3, hW1, hb1, hW2, hb2, hW3, hb3,
                                 gW1, gb1, gW2, gb2, projW, projb, ctx16, out);
}

// Round 4
// 445.164 us; speedup vs baseline: 9.5264x; 1.2852x over previous
//
#include <hip/hip_runtime.h>

// RallyNet latent-SDE, round 4.
// k_gtab: build diag-g PWL table (32 blocks) into d_ws.
// k_gru : GRU + encoder, 1 barrier/step, weights pinned in registers,
//         ctx stored straight from D-fragments (f16 into d_out alias).
// k_sde : 3 barriers/step; y held in A-fragment registers (8 f32/lane);
//         update computed redundantly by all waves in-register; f/h/noise
//         via conflict-free float4 LDS reads; logqp via shfl reduce.
// T=100, B=4096, D=32, L=32, C=64, H=128. 256 blocks x 512 threads.

#define TT 100
#define BB 4096
#define DD 32
#define LL 32
#define CC 64
#define HH 128
#define GROW 260  // g-table row stride (257 knots + pad)

typedef _Float16 h1;
typedef _Float16 h2 __attribute__((ext_vector_type(2)));
typedef _Float16 f16x8 __attribute__((ext_vector_type(8)));
typedef float f32x4 __attribute__((ext_vector_type(4)));

#define MFMA(a, b, c) __builtin_amdgcn_mfma_f32_16x16x32_f16(a, b, c, 0, 0, 0)
#define PIN(x) asm volatile("" : "+v"(x))

__device__ __forceinline__ float sigm(float x) {
  return 1.0f / (1.0f + __expf(-x));
}
__device__ __forceinline__ float tanh_(float x) {
  float xc = fminf(fmaxf(x, -15.0f), 15.0f);
  float e = __expf(2.0f * xc);
  return (e - 1.0f) / (e + 1.0f);
}
__device__ __forceinline__ float splus(float x) {
  float t = __logf(1.0f + __expf(fminf(x, 15.0f)));
  return x > 15.0f ? x : t;
}

// B-fragment of row-major W[N][K] tile (n0,k0): lane l reg j ->
// B[k0+(l>>4)*8+j][n0+(l&15)]
__device__ __forceinline__ f16x8 bfrag(const float* __restrict__ W, int K,
                                       int n0, int k0, int lane) {
  const float* p = W + (size_t)(n0 + (lane & 15)) * K + k0 + ((lane >> 4) << 3);
  f16x8 r;
#pragma unroll
  for (int j = 0; j < 8; ++j) r[j] = (h1)p[j];
  return r;
}

// A-fragment from LDS row-major tile (ld f16/row, rows 16B-aligned)
__device__ __forceinline__ f16x8 afrag(const h1* base, int ld, int k0,
                                       int lane) {
  return *(const f16x8*)(base + (size_t)(lane & 15) * ld + k0 +
                         ((lane >> 4) << 3));
}

// ---------------- g-table build: 32 blocks x 320 threads ----------------
__global__ __launch_bounds__(320) void k_gtab(
    const float* __restrict__ gW1, const float* __restrict__ gb1,
    const float* __restrict__ gW2, const float* __restrict__ gb2,
    float* __restrict__ gtab) {
  const int l = blockIdx.x;
  const int e = threadIdx.x;
  if (e >= 257) return;
  const float yv = -12.f + (float)e * (24.f / 256.f);
  const float* w1 = gW1 + l * HH;
  const float* bb = gb1 + l * HH;
  const float* w2 = gW2 + l * HH;
  float a = 0.f;
#pragma unroll 4
  for (int h = 0; h < HH; ++h)
    a = fmaf(splus(fmaf(yv, w1[h], bb[h])), w2[h], a);
  gtab[l * GROW + e] = sigm(a + gb2[l]);
}

// ---------------- Kernel 1: GRU + encoder, 1 barrier/step ----------------
__global__ __launch_bounds__(512, 2) void k_gru(
    const float* __restrict__ xs, const float* __restrict__ Wih,
    const float* __restrict__ Whh, const float* __restrict__ bih,
    const float* __restrict__ bhh, const float* __restrict__ encW,
    const float* __restrict__ encb, h1* __restrict__ ctx16) {
  __shared__ alignas(16) h1 sH[2][16][136];  // 272B rows, 2-way banks
  __shared__ alignas(16) h1 sX[2][16][40];   // 80B rows
  __shared__ float sBih[384], sBhh[384], sEncB[64];

  const int tid = threadIdx.x;
  const int lane = tid & 63, w = tid >> 6;
  const int b0 = blockIdx.x * 16;
  const int coln = lane & 15, row4 = (lane >> 4) << 2;

  for (int i = tid; i < 384; i += 512) { sBih[i] = bih[i]; sBhh[i] = bhh[i]; }
  if (tid < 64) sEncB[tid] = encb[tid];

  f16x8 wIH[3], wHH[3][4], wE[4];
#pragma unroll
  for (int g = 0; g < 3; ++g) {
    wIH[g] = bfrag(Wih, DD, 128 * g + 16 * w, 0, lane);
#pragma unroll
    for (int kt = 0; kt < 4; ++kt)
      wHH[g][kt] = bfrag(Whh, HH, 128 * g + 16 * w, 32 * kt, lane);
  }
  if (w >= 4) {
#pragma unroll
    for (int kt = 0; kt < 4; ++kt)
      wE[kt] = bfrag(encW, HH, 16 * (w - 4), 32 * kt, lane);
  }

  for (int i = tid; i < 16 * 136; i += 512) (&sH[0][0][0])[i] = (h1)0.0f;
  sX[0][tid >> 5][tid & 31] = (h1)xs[(size_t)b0 * DD + tid];
  float xHold = xs[(size_t)1 * BB * DD + (size_t)b0 * DD + tid];  // x(1)
  float hold[4] = {0.f, 0.f, 0.f, 0.f};
  __syncthreads();

  const int m = 16 * w + coln;
  const float b_r = sBih[m] + sBhh[m];
  const float b_z = sBih[128 + m] + sBhh[128 + m];
  const float b_ni = sBih[256 + m];
  const float b_nh = sBhh[256 + m];
  const float bE = (w >= 4) ? sEncB[16 * (w - 4) + coln] : 0.f;

  for (int t = 0; t < TT; ++t) {
    const int cur = t & 1;
    // depth-2 prefetch: issue x(t+2) now, stage x(t+1)=xHold this step
    const int tf = (t + 2 < TT) ? (t + 2) : (TT - 1);
    const float xFly = xs[(size_t)tf * BB * DD + (size_t)b0 * DD + tid];

#pragma unroll
    for (int g = 0; g < 3; ++g) {
      PIN(wIH[g]);
#pragma unroll
      for (int kt = 0; kt < 4; ++kt) PIN(wHH[g][kt]);
    }
    if (w >= 4) {
#pragma unroll
      for (int kt = 0; kt < 4; ++kt) PIN(wE[kt]);
    }

    // gates
    f16x8 ax = afrag(&sX[cur][0][0], 40, 0, lane);
    f32x4 aR{0, 0, 0, 0}, aZ{0, 0, 0, 0}, aNI{0, 0, 0, 0}, aNH{0, 0, 0, 0};
    aR = MFMA(ax, wIH[0], aR);
    aZ = MFMA(ax, wIH[1], aZ);
    aNI = MFMA(ax, wIH[2], aNI);
#pragma unroll
    for (int kt = 0; kt < 4; ++kt) {
      f16x8 ah = afrag(&sH[cur][0][0], 136, 32 * kt, lane);
      aR = MFMA(ah, wHH[0][kt], aR);
      aZ = MFMA(ah, wHH[1][kt], aZ);
      aNH = MFMA(ah, wHH[2][kt], aNH);
    }
#pragma unroll
    for (int j = 0; j < 4; ++j) {
      float rg = sigm(aR[j] + b_r);
      float zg = sigm(aZ[j] + b_z);
      float ng = tanh_(aNI[j] + b_ni + rg * (aNH[j] + b_nh));
      float hn = (1.0f - zg) * ng + zg * hold[j];
      hold[j] = hn;
      sH[cur ^ 1][row4 + j][m] = (h1)hn;
    }
    sX[cur ^ 1][tid >> 5][tid & 31] = (h1)xHold;  // x(t+1), arrived long ago
    __syncthreads();  // the ONLY barrier per step

    // encoder from updated h; store ctx straight from D-fragments
    if (w >= 4) {
      f32x4 aE{0, 0, 0, 0};
#pragma unroll
      for (int kt = 0; kt < 4; ++kt)
        aE = MFMA(afrag(&sH[cur ^ 1][0][0], 136, 32 * kt, lane), wE[kt], aE);
      const int cc = 16 * (w - 4) + coln;
#pragma unroll
      for (int j = 0; j < 4; ++j)
        ctx16[((size_t)t * BB + b0 + row4 + j) * CC + cc] = (h1)(aE[j] + bE);
    }
    xHold = xFly;  // vmcnt wait lands here, ~full step after issue
  }
}

// ---------------- Kernel 2: z0 + SDE scan + projection ----------------
__global__ __launch_bounds__(512, 2) void k_sde(
    const float* __restrict__ ts, const float* __restrict__ eps0,
    const float* __restrict__ noise, const float* __restrict__ qz0W,
    const float* __restrict__ qz0b, const float* __restrict__ fW1,
    const float* __restrict__ fb1, const float* __restrict__ fW2,
    const float* __restrict__ fb2, const float* __restrict__ fW3,
    const float* __restrict__ fb3, const float* __restrict__ hW1,
    const float* __restrict__ hb1, const float* __restrict__ hW2,
    const float* __restrict__ hb2, const float* __restrict__ hW3,
    const float* __restrict__ hb3, const float* __restrict__ projW,
    const float* __restrict__ projb, const float* __restrict__ gtab,
    const h1* __restrict__ ctx16, float* __restrict__ out) {
  __shared__ alignas(16) h1 sC[2][16][72];  // ctx f16, 144B rows
  __shared__ alignas(16) h1 sA1[16][136], sB1[16][136];
  __shared__ alignas(16) h1 sA2[16][136], sB2[16][136];
  __shared__ alignas(16) float sFv[16][36], sHv[16][36];  // f,h outs (f32)
  __shared__ alignas(16) float sN[2][16][36];             // noise staging
  __shared__ float sG[32][GROW];
  __shared__ float sDt[112], sSq[112];
  __shared__ float sFB1[128], sHB1[128], sFB2[128], sHB2[128];
  __shared__ float sFB3[32], sHB3[32], sPjB[32];

  const int tid = threadIdx.x;
  const int lane = tid & 63, w = tid >> 6;
  const int b0 = blockIdx.x * 16;
  const int coln = lane & 15, row4 = (lane >> 4) << 2;
  const int sr = tid >> 5, sc = tid & 31;  // thread-linear staging map

  for (int i = tid; i < 128; i += 512) {
    sFB1[i] = fb1[i]; sHB1[i] = hb1[i]; sFB2[i] = fb2[i]; sHB2[i] = hb2[i];
  }
  if (tid < 32) { sFB3[tid] = fb3[tid]; sHB3[tid] = hb3[tid]; sPjB[tid] = projb[tid]; }
  if (tid < TT - 1) {
    float d = ts[tid + 1] - ts[tid];
    sDt[tid] = d;
    sSq[tid] = __fsqrt_rn(d);
  }
  for (int i = tid; i < 32 * GROW; i += 512) (&sG[0][0])[i] = gtab[i];
  // stage ctx[0], noise[0]
  *(h2*)&sC[0][sr][2 * sc] = *(const h2*)(ctx16 + (size_t)(b0 + sr) * CC + 2 * sc);
  sN[0][sr][sc] = noise[(size_t)(b0 + sr) * LL + sc];

  // register-resident weight fragments
  f16x8 wF1[3], wH1v, wF2[4], wH2[4], wP3[4], wPj;
#pragma unroll
  for (int kt = 0; kt < 3; ++kt) wF1[kt] = bfrag(fW1, 96, 16 * w, 32 * kt, lane);
  wH1v = bfrag(hW1, 32, 16 * w, 0, lane);
#pragma unroll
  for (int kt = 0; kt < 4; ++kt) {
    wF2[kt] = bfrag(fW2, HH, 16 * w, 32 * kt, lane);
    wH2[kt] = bfrag(hW2, HH, 16 * w, 32 * kt, lane);
  }
  if (w < 2) {
#pragma unroll
    for (int kt = 0; kt < 4; ++kt) wP3[kt] = bfrag(fW3, HH, 16 * w, 32 * kt, lane);
  } else if (w < 4) {
#pragma unroll
    for (int kt = 0; kt < 4; ++kt) wP3[kt] = bfrag(hW3, HH, 16 * (w - 2), 32 * kt, lane);
  } else if (w >= 6) {
    wPj = bfrag(projW, LL, 16 * (w - 6), 0, lane);
  }
  __syncthreads();

  // z0 per-thread scalar -> sFv staging
  {
    float m0 = qz0b[sc], s0 = qz0b[32 + sc];
    const float* qm = qz0W + sc * 64;
    const float* qs = qz0W + (32 + sc) * 64;
#pragma unroll 4
    for (int k = 0; k < 64; ++k) {
      float cv = (float)sC[0][sr][k];
      m0 = fmaf(qm[k], cv, m0);
      s0 = fmaf(qs[k], cv, s0);
    }
    sFv[sr][sc] = fmaf(__expf(s0), eps0[(size_t)(b0 + sr) * LL + sc], m0);
  }
  __syncthreads();

  // y into A-fragment registers: yv[j] = y[lane&15][(lane>>4)*8+j]
  float yv[8];
  {
    const int ck = (lane >> 4) << 3;
    f32x4 a = *(const f32x4*)&sFv[lane & 15][ck];
    f32x4 b = *(const f32x4*)&sFv[lane & 15][ck + 4];
#pragma unroll
    for (int j = 0; j < 4; ++j) { yv[j] = a[j]; yv[4 + j] = b[j]; }
  }
  float lqp = 0.f;

  for (int t = 0; t < TT - 1; ++t) {
    const int cur = t & 1;
    // issue prefetches for t+1 (staged to LDS in P2)
    const int tn = (t + 1 < TT - 1) ? (t + 1) : (TT - 2);
    const h2 cpre =
        *(const h2*)(ctx16 + ((size_t)(t + 1) * BB + b0 + sr) * CC + 2 * sc);
    const float npre = noise[((size_t)tn * BB + b0 + sr) * LL + sc];

#pragma unroll
    for (int kt = 0; kt < 3; ++kt) PIN(wF1[kt]);
    PIN(wH1v);
#pragma unroll
    for (int kt = 0; kt < 4; ++kt) { PIN(wF2[kt]); PIN(wH2[kt]); }
    if (w < 4) {
#pragma unroll
      for (int kt = 0; kt < 4; ++kt) PIN(wP3[kt]);
    } else if (w >= 6) {
      PIN(wPj);
    }

    f16x8 aYf;
#pragma unroll
    for (int j = 0; j < 8; ++j) aYf[j] = (h1)yv[j];

    // ---- P1: a1 = sp(fW1*[y;c]+b), b1 = sp(hW1*y+b) ----
    {
      f16x8 aC0 = afrag(&sC[cur][0][0], 72, 0, lane);
      f16x8 aC1 = afrag(&sC[cur][0][0], 72, 32, lane);
      f32x4 aF{0, 0, 0, 0}, aH{0, 0, 0, 0};
      aF = MFMA(aYf, wF1[0], aF);
      aF = MFMA(aC0, wF1[1], aF);
      aF = MFMA(aC1, wF1[2], aF);
      aH = MFMA(aYf, wH1v, aH);
      const int cc = 16 * w + coln;
      const float bF = sFB1[cc], bH = sHB1[cc];
#pragma unroll
      for (int j = 0; j < 4; ++j) {
        sA1[row4 + j][cc] = (h1)splus(aF[j] + bF);
        sB1[row4 + j][cc] = (h1)splus(aH[j] + bH);
      }
    }
    __syncthreads();  // BAR1

    // ---- P2: a2, b2; stage prefetched ctx/noise ----
    {
      f32x4 aF{0, 0, 0, 0}, aH{0, 0, 0, 0};
#pragma unroll
      for (int kt = 0; kt < 4; ++kt) {
        aF = MFMA(afrag(&sA1[0][0], 136, 32 * kt, lane), wF2[kt], aF);
        aH = MFMA(afrag(&sB1[0][0], 136, 32 * kt, lane), wH2[kt], aH);
      }
      const int cc = 16 * w + coln;
      const float bF = sFB2[cc], bH = sHB2[cc];
#pragma unroll
      for (int j = 0; j < 4; ++j) {
        sA2[row4 + j][cc] = (h1)splus(aF[j] + bF);
        sB2[row4 + j][cc] = (h1)splus(aH[j] + bH);
      }
    }
    *(h2*)&sC[cur ^ 1][sr][2 * sc] = cpre;
    sN[cur ^ 1][sr][sc] = npre;
    __syncthreads();  // BAR2

    // ---- P3: f (w0-1), hdr (w2-3), proj zs[t] (w6-7) ----
    if (w < 2) {
      f32x4 acc{0, 0, 0, 0};
#pragma unroll
      for (int kt = 0; kt < 4; ++kt)
        acc = MFMA(afrag(&sA2[0][0], 136, 32 * kt, lane), wP3[kt], acc);
      const int cc = 16 * w + coln;
#pragma unroll
      for (int j = 0; j < 4; ++j) sFv[row4 + j][cc] = acc[j] + sFB3[cc];
    } else if (w < 4) {
      f32x4 acc{0, 0, 0, 0};
#pragma unroll
      for (int kt = 0; kt < 4; ++kt)
        acc = MFMA(afrag(&sB2[0][0], 136, 32 * kt, lane), wP3[kt], acc);
      const int cc = 16 * (w - 2) + coln;
#pragma unroll
      for (int j = 0; j < 4; ++j) sHv[row4 + j][cc] = acc[j] + sHB3[cc];
    } else if (w >= 6) {
      f32x4 acc{0, 0, 0, 0};
      acc = MFMA(aYf, wPj, acc);
      const int cc = 16 * (w - 6) + coln;
#pragma unroll
      for (int j = 0; j < 4; ++j)
        out[((size_t)t * BB + b0 + row4 + j) * DD + cc] = acc[j] + sPjB[cc];
    }
    __syncthreads();  // BAR3

    // ---- update, in-register, redundant across waves (no barrier) ----
    {
      const float dtv = sDt[t], sqdt = sSq[t];
      const int rr = lane & 15, ck = (lane >> 4) << 3;
      const f32x4 fA = *(const f32x4*)&sFv[rr][ck];
      const f32x4 fB = *(const f32x4*)&sFv[rr][ck + 4];
      const f32x4 hA = *(const f32x4*)&sHv[rr][ck];
      const f32x4 hB = *(const f32x4*)&sHv[rr][ck + 4];
      const f32x4 nA = *(const f32x4*)&sN[cur][rr][ck];
      const f32x4 nB = *(const f32x4*)&sN[cur][rr][ck + 4];
#pragma unroll
      for (int j = 0; j < 4; ++j) {
        // slot j
        {
          float p = fminf(fmaxf(fmaf(yv[j], 32.f / 3.f, 128.f), 0.f), 255.999f);
          const int i = (int)p;
          const float fr = p - (float)i;
          const float* g = sG[ck + j];
          const float gv = fmaf(g[i + 1] - g[i], fr, g[i]);
          const float uv = (fA[j] - hA[j]) / gv;
          lqp = fmaf(0.5f * uv * uv, dtv, lqp);
          yv[j] = fmaf(fA[j], dtv, yv[j]) + gv * sqdt * nA[j];
        }
        // slot j+4
        {
          float p = fminf(fmaxf(fmaf(yv[4 + j], 32.f / 3.f, 128.f), 0.f), 255.999f);
          const int i = (int)p;
          const float fr = p - (float)i;
          const float* g = sG[ck + 4 + j];
          const float gv = fmaf(g[i + 1] - g[i], fr, g[i]);
          const float uv = (fB[j] - hB[j]) / gv;
          lqp = fmaf(0.5f * uv * uv, dtv, lqp);
          yv[4 + j] = fmaf(fB[j], dtv, yv[4 + j]) + gv * sqdt * nB[j];
        }
      }
    }
  }

  // final projection xs_hat[99] from z_99 (registers only)
  if (w >= 6) {
    f16x8 aYf;
#pragma unroll
    for (int j = 0; j < 8; ++j) aYf[j] = (h1)yv[j];
    f32x4 acc{0, 0, 0, 0};
    acc = MFMA(aYf, wPj, acc);
    const int cc = 16 * (w - 6) + coln;
#pragma unroll
    for (int j = 0; j < 4; ++j)
      out[((size_t)(TT - 1) * BB + b0 + row4 + j) * DD + cc] = acc[j] + sPjB[cc];
  }
  // logqp: sum lane groups {r, r+16, r+32, r+48}
  lqp += __shfl_xor(lqp, 16);
  lqp += __shfl_xor(lqp, 32);
  if (w == 0 && lane < 16) out[(size_t)TT * BB * DD + b0 + lane] = lqp;
}

extern "C" void kernel_launch(void* const* d_in, const int* in_sizes, int n_in,
                              void* d_out, int out_size, void* d_ws,
                              size_t ws_size, hipStream_t stream) {
  const float* xs = (const float*)d_in[0];
  const float* ts = (const float*)d_in[1];
  const float* eps0 = (const float*)d_in[2];
  const float* noise = (const float*)d_in[3];
  const float* Wih = (const float*)d_in[4];
  const float* Whh = (const float*)d_in[5];
  const float* bih = (const float*)d_in[6];
  const float* bhh = (const float*)d_in[7];
  const float* encW = (const float*)d_in[8];
  const float* encb = (const float*)d_in[9];
  const float* qz0W = (const float*)d_in[10];
  const float* qz0b = (const float*)d_in[11];
  const float* fW1 = (const float*)d_in[12];
  const float* fb1 = (const float*)d_in[13];
  const float* fW2 = (const float*)d_in[14];
  const float* fb2 = (const float*)d_in[15];
  const float* fW3 = (const float*)d_in[16];
  const float* fb3 = (const float*)d_in[17];
  const float* hW1 = (const float*)d_in[18];
  const float* hb1 = (const float*)d_in[19];
  const float* hW2 = (const float*)d_in[20];
  const float* hb2 = (const float*)d_in[21];
  const float* hW3 = (const float*)d_in[22];
  const float* hb3 = (const float*)d_in[23];
  const float* gW1 = (const float*)d_in[24];
  const float* gb1 = (const float*)d_in[25];
  const float* gW2 = (const float*)d_in[26];
  const float* gb2 = (const float*)d_in[27];
  const float* projW = (const float*)d_in[28];
  const float* projb = (const float*)d_in[29];
  float* out = (float*)d_out;
  h1* ctx16 = (h1*)d_out;      // ctx[t,b,64] f16 aliases xs_hat[t,b,32] f32
  float* gtab = (float*)d_ws;  // 32*260*4 = 33,280 B

  k_gtab<<<32, 320, 0, stream>>>(gW1, gb1, gW2, gb2, gtab);
  k_gru<<<256, 512, 0, stream>>>(xs, Wih, Whh, bih, bhh, encW, encb, ctx16);
  k_sde<<<256, 512, 0, stream>>>(ts, eps0, noise, qz0W, qz0b, fW1, fb1, fW2,
                                 fb2, fW3, fb3, hW1, hb1, hW2, hb2, hW3, hb3,
                                 projW, projb, gtab, ctx16, out);
}